// Round 4
// baseline (895.147 us; speedup 1.0000x reference)
//
#include <hip/hip_runtime.h>

// T=1024, B=256, D=64, H=128, fp32 in/out.
// Z = d_ws (T*B*H fp32). k_feat_mfma writes z_t = tanh(x Wx^T+bx) Wih^T +
// (bih+bhh). k_scan_mfma (16 batch/WG, 16 WGs) runs h'=tanh(z_t + h Whh^T)
// via f16 MFMA, overwriting slot t with h_{t+1}. k_out_mfma reads slot r-256
// (= pre-update h) and computes y = tanh(h Wh^T + bh) Wg^T + bg.

#define T_SEQ 1024
#define B_SZ  256
#define D_IN  64
#define H_DIM 128

typedef __attribute__((ext_vector_type(8))) _Float16 half8;
typedef __attribute__((ext_vector_type(4))) _Float16 half4;
typedef __attribute__((ext_vector_type(4))) float f32x4;

__device__ __forceinline__ float fast_tanh(float x) {
  float ax = __builtin_fabsf(x);
  float e  = __builtin_amdgcn_exp2f(ax * -2.8853900817779268f); // -2*log2(e)
  float r  = (1.0f - e) * __builtin_amdgcn_rcpf(1.0f + e);
  return __builtin_copysignf(r, x);
}

// barrier waiting ONLY lgkmcnt (LDS): vm=63, exp=7, lgkm=0 -> imm 0xC07F
__device__ __forceinline__ void barrier_lds_only() {
  __asm__ __volatile__("" ::: "memory");
  __builtin_amdgcn_s_waitcnt(0xC07F);
  __builtin_amdgcn_s_barrier();
  __asm__ __volatile__("" ::: "memory");
}

__device__ __forceinline__ half8 pack_h8(float4 a, float4 b) {
  half8 s = { (_Float16)a.x, (_Float16)a.y, (_Float16)a.z, (_Float16)a.w,
              (_Float16)b.x, (_Float16)b.y, (_Float16)b.z, (_Float16)b.w };
  return s;
}

// ---------------------------------------------------------------------------
// Kernel 1 (f16 MFMA): z = tanh(x Wx^T + bx) Wih^T + (bih+bhh)
// 512 WGs x 8 tiles of 64 rows. Wave wv owns rows [wv*16, wv*16+16).
// Wx frags in registers (64 VGPR); Wih f16 in LDS; feat LDS round-trip.
// ---------------------------------------------------------------------------
#define WI_S 136
#define XT_S 72
#define FM_S 136

__global__ __launch_bounds__(256) void k_feat_mfma(
    const float* __restrict__ x,  const float* __restrict__ Wx,
    const float* __restrict__ bx, const float* __restrict__ Wih,
    const float* __restrict__ bih,const float* __restrict__ bhh,
    float* __restrict__ Z)
{
  __shared__ __align__(16) _Float16 wi_l[128 * WI_S]; // 34816 B
  __shared__ __align__(16) _Float16 xt_l[64 * XT_S];  //  9216 B
  __shared__ __align__(16) _Float16 fm_l[64 * FM_S];  // 17408 B  (61440 total)

  const int tid = threadIdx.x;
  const int l   = tid & 63;
  const int wv  = tid >> 6;
  const int ln  = l & 15;
  const int kg  = l >> 4;

  // stage Wih -> LDS f16
  {
    const float4* w4 = (const float4*)Wih;     // 128x128 = 4096 float4
#pragma unroll
    for (int p = 0; p < 16; ++p) {
      int f = tid + p * 256;
      int row = f >> 5, kc = (f & 31) * 4;
      float4 v = w4[f];
      half4 s = { (_Float16)v.x, (_Float16)v.y, (_Float16)v.z, (_Float16)v.w };
      *(half4*)&wi_l[row * WI_S + kc] = s;
    }
  }
  // Wx B-frags -> registers (n = nt*16+ln, k = kf*32 + kg*8 + j)
  half8 wxr[8][2];
#pragma unroll
  for (int nt = 0; nt < 8; ++nt)
#pragma unroll
    for (int kf = 0; kf < 2; ++kf) {
      const float* wp = Wx + (nt*16 + ln) * D_IN + kf*32 + kg*8;
      wxr[nt][kf] = pack_h8(*(const float4*)wp, *(const float4*)(wp + 4));
    }

  float bx_r[8], b2_r[8];
#pragma unroll
  for (int nt = 0; nt < 8; ++nt) {
    bx_r[nt] = bx[nt*16 + ln];
    b2_r[nt] = bih[nt*16 + ln] + bhh[nt*16 + ln];
  }

  for (int it = 0; it < 8; ++it) {
    const long tile = blockIdx.x * 8 + it;
    const long r0   = tile * 64;

    // stage x tile (64 x 64 fp32 -> f16)
    {
      const float4* x4 = (const float4*)x;     // row stride 16 float4
#pragma unroll
      for (int p = 0; p < 4; ++p) {
        int f = tid + p * 256;                 // 1024 float4
        int row = f >> 4, kc = (f & 15) * 4;
        float4 v = x4[r0 * 16 + f];
        half4 s = { (_Float16)v.x, (_Float16)v.y, (_Float16)v.z, (_Float16)v.w };
        *(half4*)&xt_l[row * XT_S + kc] = s;
      }
    }
    barrier_lds_only();

    // GEMM1: feat = tanh(x @ Wx^T + bx)
    half8 a1[2];
#pragma unroll
    for (int kf = 0; kf < 2; ++kf)
      a1[kf] = *(const half8*)&xt_l[(wv*16 + ln) * XT_S + kf*32 + kg*8];

#pragma unroll
    for (int nt = 0; nt < 8; ++nt) {
      f32x4 acc = {0.f, 0.f, 0.f, 0.f};
#pragma unroll
      for (int kf = 0; kf < 2; ++kf)
        acc = __builtin_amdgcn_mfma_f32_16x16x32_f16(a1[kf], wxr[nt][kf], acc, 0, 0, 0);
#pragma unroll
      for (int c = 0; c < 4; ++c) {
        float v = fast_tanh(acc[c] + bx_r[nt]);
        fm_l[(wv*16 + kg*4 + c) * FM_S + nt*16 + ln] = (_Float16)v;
      }
    }
    // fm rows [wv*16,wv*16+16) written & read by same wave: compiler lgkm dep

    // GEMM2: z = feat @ Wih^T + (bih+bhh)
    half8 a2[4];
#pragma unroll
    for (int kf = 0; kf < 4; ++kf)
      a2[kf] = *(const half8*)&fm_l[(wv*16 + ln) * FM_S + kf*32 + kg*8];

#pragma unroll
    for (int nt = 0; nt < 8; ++nt) {
      f32x4 acc = { b2_r[nt], b2_r[nt], b2_r[nt], b2_r[nt] };
#pragma unroll
      for (int kf = 0; kf < 4; ++kf) {
        half8 bf = *(const half8*)&wi_l[(nt*16 + ln) * WI_S + kf*32 + kg*8];
        acc = __builtin_amdgcn_mfma_f32_16x16x32_f16(a2[kf], bf, acc, 0, 0, 0);
      }
#pragma unroll
      for (int c = 0; c < 4; ++c)
        Z[(r0 + wv*16 + kg*4 + c) * H_DIM + nt*16 + ln] = acc[c];
    }
    barrier_lds_only();   // xt_l/fm_l safe before next tile staging
  }
}

// ---------------------------------------------------------------------------
// Kernel 2 (f16 MFMA batched scan): 16 batch elems/WG, 16 WGs, 4 waves.
// Wave wv owns n-slice [wv*32, wv*32+32) (2 n-tiles). Per step: read h A-frags
// from LDS, 2x4 chained MFMA -> C[16 batch x 16 n], add z, tanh, write h' to
// the other LDS buffer in A-layout + fp32 to Z. One lgkm-only barrier/step.
// ---------------------------------------------------------------------------
__global__ __launch_bounds__(256) void k_scan_mfma(
    const float* __restrict__ Whh, float* __restrict__ Z)
{
  __shared__ __align__(16) _Float16 h_l[2][16 * 136];

  const int tid = threadIdx.x;
  const int l   = tid & 63;
  const int wv  = tid >> 6;
  const int ln  = l & 15;
  const int kg  = l >> 4;
  const int b0  = blockIdx.x * 16;

  // Whh B-frags (n = wv*32 + nt*16 + ln)
  half8 wr[2][4];
#pragma unroll
  for (int nt = 0; nt < 2; ++nt)
#pragma unroll
    for (int kf = 0; kf < 4; ++kf) {
      const float* wp = Whh + (wv*32 + nt*16 + ln) * H_DIM + kf*32 + kg*8;
      wr[nt][kf] = pack_h8(*(const float4*)wp, *(const float4*)(wp + 4));
    }

  for (int i = tid; i < 2 * 16 * 136; i += 256) ((_Float16*)h_l)[i] = (_Float16)0.f;

  // z/h global offsets: e = nt*4+c -> row b0+kg*4+c, col wv*32+nt*16+ln
  int zoff[8];
#pragma unroll
  for (int nt = 0; nt < 2; ++nt)
#pragma unroll
    for (int c = 0; c < 4; ++c)
      zoff[nt*4 + c] = (b0 + kg*4 + c) * H_DIM + wv*32 + nt*16 + ln;

  float zb[4][8];
#pragma unroll
  for (int p = 0; p < 4; ++p)
#pragma unroll
    for (int e = 0; e < 8; ++e)
      zb[p][e] = Z[(long)p * (B_SZ * H_DIM) + zoff[e]];

  barrier_lds_only();

  for (int tb = 0; tb < T_SEQ; tb += 4) {
#pragma unroll
    for (int u = 0; u < 4; ++u) {
      const int t = tb + u;
      const _Float16* hb = h_l[t & 1];
      _Float16*       hn = h_l[(t & 1) ^ 1];

      half8 af[4];
#pragma unroll
      for (int kf = 0; kf < 4; ++kf)
        af[kf] = *(const half8*)&hb[ln * 136 + kf*32 + kg*8];

      f32x4 acc0 = {0.f, 0.f, 0.f, 0.f};
      f32x4 acc1 = {0.f, 0.f, 0.f, 0.f};
#pragma unroll
      for (int kf = 0; kf < 4; ++kf)
        acc0 = __builtin_amdgcn_mfma_f32_16x16x32_f16(af[kf], wr[0][kf], acc0, 0, 0, 0);
#pragma unroll
      for (int kf = 0; kf < 4; ++kf)
        acc1 = __builtin_amdgcn_mfma_f32_16x16x32_f16(af[kf], wr[1][kf], acc1, 0, 0, 0);

#pragma unroll
      for (int nt = 0; nt < 2; ++nt)
#pragma unroll
        for (int c = 0; c < 4; ++c) {
          const int e = nt*4 + c;
          float v  = (nt ? acc1[c] : acc0[c]) + zb[u][e];
          float hv = fast_tanh(v);
          hn[(kg*4 + c) * 136 + wv*32 + nt*16 + ln] = (_Float16)hv;  // A-layout
          Z[(long)t * (B_SZ * H_DIM) + zoff[e]] = hv;                // for k_out
          zb[u][e] = (t + 4 < T_SEQ)
                   ? Z[(long)(t + 4) * (B_SZ * H_DIM) + zoff[e]] : 0.f;
        }
      barrier_lds_only();
    }
  }
}

// ---------------------------------------------------------------------------
// Kernel 3 (f16 MFMA): y = tanh(h Wh^T + bh) Wg^T + bg.  (R3 structure,
// bf16 -> f16 for 4x smaller rounding error)
// ---------------------------------------------------------------------------
#define TILE_R 64
#define TPW    8
#define HM_S   136
#define WH_S   136

__global__ __launch_bounds__(256) void k_out_mfma(
    const float* __restrict__ Zh, const float* __restrict__ Wh,
    const float* __restrict__ bh, const float* __restrict__ Wg,
    const float* __restrict__ bg, float* __restrict__ y)
{
  __shared__ __align__(16) _Float16 wh_l[128 * WH_S];   // 34816 B
  __shared__ __align__(16) _Float16 hm_l[TILE_R * HM_S]; // 17408 B

  const int tid = threadIdx.x;
  const int l   = tid & 63;
  const int wv  = tid >> 6;
  const int ln  = l & 15;
  const int kg  = l >> 4;

  {
    const float4* wg4 = (const float4*)Wh;
#pragma unroll
    for (int p = 0; p < 16; ++p) {
      int f = tid + p * 256;
      int row = f >> 5, kc = (f & 31) * 4;
      float4 v = wg4[f];
      half4 s = { (_Float16)v.x, (_Float16)v.y, (_Float16)v.z, (_Float16)v.w };
      *(half4*)&wh_l[row * WH_S + kc] = s;
    }
  }

  half8 wg_r[4][4];
#pragma unroll
  for (int nt2 = 0; nt2 < 4; ++nt2)
#pragma unroll
    for (int ks = 0; ks < 4; ++ks) {
      const float* wp = Wg + (nt2*16 + ln) * H_DIM + ks*32 + kg*8;
      wg_r[nt2][ks] = pack_h8(*(const float4*)wp, *(const float4*)(wp + 4));
    }

  float bh_r[8], bg_r[4];
#pragma unroll
  for (int nt = 0; nt < 8; ++nt) bh_r[nt] = bh[nt*16 + ln];
#pragma unroll
  for (int nt2 = 0; nt2 < 4; ++nt2) bg_r[nt2] = bg[nt2*16 + ln];

  for (int it = 0; it < TPW; ++it) {
    const int tile = blockIdx.x * TPW + it;
    const long r0  = (long)tile * TILE_R;
    const bool zero = (tile < 4);        // rows < 256 -> t==0 -> h = 0

    {
      const float4* hg = (const float4*)(Zh + (r0 - 256) * H_DIM);
#pragma unroll
      for (int p = 0; p < 8; ++p) {
        int f = tid + p * 256;
        int row = f >> 5, kc = (f & 31) * 4;
        float4 v;
        if (zero) { v.x = v.y = v.z = v.w = 0.f; } else { v = hg[f]; }
        half4 s = { (_Float16)v.x, (_Float16)v.y, (_Float16)v.z, (_Float16)v.w };
        *(half4*)&hm_l[row * HM_S + kc] = s;
      }
    }
    barrier_lds_only();

    half8 af[4];
#pragma unroll
    for (int ks = 0; ks < 4; ++ks)
      af[ks] = *(const half8*)&hm_l[(wv*16 + ln) * HM_S + ks*32 + kg*8];

#pragma unroll
    for (int nt = 0; nt < 8; ++nt) {
      f32x4 acc = {0.f, 0.f, 0.f, 0.f};
#pragma unroll
      for (int ks = 0; ks < 4; ++ks) {
        half8 bf = *(const half8*)&wh_l[(nt*16 + ln) * WH_S + ks*32 + kg*8];
        acc = __builtin_amdgcn_mfma_f32_16x16x32_f16(af[ks], bf, acc, 0, 0, 0);
      }
#pragma unroll
      for (int c = 0; c < 4; ++c) {
        float val = fast_tanh(acc[c] + bh_r[nt]);
        hm_l[(wv*16 + kg*4 + c) * HM_S + nt*16 + ln] = (_Float16)val;
      }
    }
    // same-wave LDS RAW: compiler lgkm wait

    half8 a2[4];
#pragma unroll
    for (int ks = 0; ks < 4; ++ks)
      a2[ks] = *(const half8*)&hm_l[(wv*16 + ln) * HM_S + ks*32 + kg*8];

#pragma unroll
    for (int nt2 = 0; nt2 < 4; ++nt2) {
      f32x4 acc2 = { bg_r[nt2], bg_r[nt2], bg_r[nt2], bg_r[nt2] };
#pragma unroll
      for (int ks = 0; ks < 4; ++ks)
        acc2 = __builtin_amdgcn_mfma_f32_16x16x32_f16(a2[ks], wg_r[nt2][ks],
                                                      acc2, 0, 0, 0);
#pragma unroll
      for (int c = 0; c < 4; ++c)
        y[(r0 + wv*16 + kg*4 + c) * D_IN + nt2*16 + ln] = acc2[c];
    }
    barrier_lds_only();
  }
}

extern "C" void kernel_launch(void* const* d_in, const int* in_sizes, int n_in,
                              void* d_out, int out_size, void* d_ws, size_t ws_size,
                              hipStream_t stream) {
  const float* x   = (const float*)d_in[0];
  const float* Wx  = (const float*)d_in[1];
  const float* bx  = (const float*)d_in[2];
  const float* Wih = (const float*)d_in[3];
  const float* bih = (const float*)d_in[4];
  const float* Whh = (const float*)d_in[5];
  const float* bhh = (const float*)d_in[6];
  const float* Wh  = (const float*)d_in[7];
  const float* bh  = (const float*)d_in[8];
  const float* Wg  = (const float*)d_in[9];
  const float* bg  = (const float*)d_in[10];
  float* Z = (float*)d_ws;              // T*B*H*4 = 134,217,728 B
  float* y = (float*)d_out;

  k_feat_mfma<<<512, 256, 0, stream>>>(x, Wx, bx, Wih, bih, bhh, Z);
  k_scan_mfma<<<16,  256, 0, stream>>>(Whh, Z);
  k_out_mfma <<<512, 256, 0, stream>>>(Z, Wh, bh, Wg, bg, y);
}

// Round 5
// 550.781 us; speedup vs baseline: 1.6252x; 1.6252x over previous
//
#include <hip/hip_runtime.h>

// T=1024, B=256, D=64, H=128, fp32 in/out.
// Z = d_ws (T*B*H fp32). k_feat_mfma writes z_t = tanh(x Wx^T+bx) Wih^T +
// (bih+bhh). k_scan (VALU, 1 WG/batch elem) runs h'=tanh(z_t + h Whh^T),
// overwriting slot t with h_{t+1}. k_out_mfma reads slot r-256 (= pre-update
// h) and computes y = tanh(h Wh^T + bh) Wg^T + bg via f16 MFMA.

#define T_SEQ 1024
#define B_SZ  256
#define D_IN  64
#define H_DIM 128

typedef __attribute__((ext_vector_type(8))) _Float16 half8;
typedef __attribute__((ext_vector_type(4))) _Float16 half4;
typedef __attribute__((ext_vector_type(4))) float f32x4;

__device__ __forceinline__ float fast_tanh(float x) {
  float ax = __builtin_fabsf(x);
  float e  = __builtin_amdgcn_exp2f(ax * -2.8853900817779268f); // -2*log2(e)
  float r  = (1.0f - e) * __builtin_amdgcn_rcpf(1.0f + e);
  return __builtin_copysignf(r, x);
}

// barrier waiting ONLY lgkmcnt (LDS): vm=63, exp=7, lgkm=0 -> imm 0xC07F
__device__ __forceinline__ void barrier_lds_only() {
  __asm__ __volatile__("" ::: "memory");
  __builtin_amdgcn_s_waitcnt(0xC07F);
  __builtin_amdgcn_s_barrier();
  __asm__ __volatile__("" ::: "memory");
}

__device__ __forceinline__ half8 pack_h8(float4 a, float4 b) {
  half8 s = { (_Float16)a.x, (_Float16)a.y, (_Float16)a.z, (_Float16)a.w,
              (_Float16)b.x, (_Float16)b.y, (_Float16)b.z, (_Float16)b.w };
  return s;
}

// 8-way lane reduction over ks=tid&7, all on VALU pipe (no DS op):
// xor1, xor2 (quad_perm), then row_half_mirror (lane^7 == lane^4 once each
// quad is uniform after the first two steps).
__device__ __forceinline__ float add_xor1(float x) {
  int v = __builtin_amdgcn_mov_dpp(__float_as_int(x), 0xB1, 0xF, 0xF, true);
  return x + __int_as_float(v);
}
__device__ __forceinline__ float add_xor2(float x) {
  int v = __builtin_amdgcn_mov_dpp(__float_as_int(x), 0x4E, 0xF, 0xF, true);
  return x + __int_as_float(v);
}
__device__ __forceinline__ float add_mirror8(float x) {
  int v = __builtin_amdgcn_mov_dpp(__float_as_int(x), 0x141, 0xF, 0xF, true);
  return x + __int_as_float(v);
}
__device__ __forceinline__ float dot4(float4 w, float4 h) {
  return fmaf(w.x, h.x, fmaf(w.y, h.y, fmaf(w.z, h.z, w.w * h.w)));
}

// ---------------------------------------------------------------------------
// Kernel 1 (f16 MFMA): z = tanh(x Wx^T + bx) Wih^T + (bih+bhh)
// (unchanged from R4)
// ---------------------------------------------------------------------------
#define WI_S 136
#define XT_S 72
#define FM_S 136

__global__ __launch_bounds__(256) void k_feat_mfma(
    const float* __restrict__ x,  const float* __restrict__ Wx,
    const float* __restrict__ bx, const float* __restrict__ Wih,
    const float* __restrict__ bih,const float* __restrict__ bhh,
    float* __restrict__ Z)
{
  __shared__ __align__(16) _Float16 wi_l[128 * WI_S]; // 34816 B
  __shared__ __align__(16) _Float16 xt_l[64 * XT_S];  //  9216 B
  __shared__ __align__(16) _Float16 fm_l[64 * FM_S];  // 17408 B

  const int tid = threadIdx.x;
  const int l   = tid & 63;
  const int wv  = tid >> 6;
  const int ln  = l & 15;
  const int kg  = l >> 4;

  {
    const float4* w4 = (const float4*)Wih;     // 128x128 = 4096 float4
#pragma unroll
    for (int p = 0; p < 16; ++p) {
      int f = tid + p * 256;
      int row = f >> 5, kc = (f & 31) * 4;
      float4 v = w4[f];
      half4 s = { (_Float16)v.x, (_Float16)v.y, (_Float16)v.z, (_Float16)v.w };
      *(half4*)&wi_l[row * WI_S + kc] = s;
    }
  }
  half8 wxr[8][2];
#pragma unroll
  for (int nt = 0; nt < 8; ++nt)
#pragma unroll
    for (int kf = 0; kf < 2; ++kf) {
      const float* wp = Wx + (nt*16 + ln) * D_IN + kf*32 + kg*8;
      wxr[nt][kf] = pack_h8(*(const float4*)wp, *(const float4*)(wp + 4));
    }

  float bx_r[8], b2_r[8];
#pragma unroll
  for (int nt = 0; nt < 8; ++nt) {
    bx_r[nt] = bx[nt*16 + ln];
    b2_r[nt] = bih[nt*16 + ln] + bhh[nt*16 + ln];
  }

  for (int it = 0; it < 8; ++it) {
    const long tile = blockIdx.x * 8 + it;
    const long r0   = tile * 64;

    {
      const float4* x4 = (const float4*)x;
#pragma unroll
      for (int p = 0; p < 4; ++p) {
        int f = tid + p * 256;
        int row = f >> 4, kc = (f & 15) * 4;
        float4 v = x4[r0 * 16 + f];
        half4 s = { (_Float16)v.x, (_Float16)v.y, (_Float16)v.z, (_Float16)v.w };
        *(half4*)&xt_l[row * XT_S + kc] = s;
      }
    }
    barrier_lds_only();

    half8 a1[2];
#pragma unroll
    for (int kf = 0; kf < 2; ++kf)
      a1[kf] = *(const half8*)&xt_l[(wv*16 + ln) * XT_S + kf*32 + kg*8];

#pragma unroll
    for (int nt = 0; nt < 8; ++nt) {
      f32x4 acc = {0.f, 0.f, 0.f, 0.f};
#pragma unroll
      for (int kf = 0; kf < 2; ++kf)
        acc = __builtin_amdgcn_mfma_f32_16x16x32_f16(a1[kf], wxr[nt][kf], acc, 0, 0, 0);
#pragma unroll
      for (int c = 0; c < 4; ++c) {
        float v = fast_tanh(acc[c] + bx_r[nt]);
        fm_l[(wv*16 + kg*4 + c) * FM_S + nt*16 + ln] = (_Float16)v;
      }
    }

    half8 a2[4];
#pragma unroll
    for (int kf = 0; kf < 4; ++kf)
      a2[kf] = *(const half8*)&fm_l[(wv*16 + ln) * FM_S + kf*32 + kg*8];

#pragma unroll
    for (int nt = 0; nt < 8; ++nt) {
      f32x4 acc = { b2_r[nt], b2_r[nt], b2_r[nt], b2_r[nt] };
#pragma unroll
      for (int kf = 0; kf < 4; ++kf) {
        half8 bf = *(const half8*)&wi_l[(nt*16 + ln) * WI_S + kf*32 + kg*8];
        acc = __builtin_amdgcn_mfma_f32_16x16x32_f16(a2[kf], bf, acc, 0, 0, 0);
      }
#pragma unroll
      for (int c = 0; c < 4; ++c)
        Z[(r0 + wv*16 + kg*4 + c) * H_DIM + nt*16 + ln] = acc[c];
    }
    barrier_lds_only();
  }
}

// ---------------------------------------------------------------------------
// Kernel 2 (VALU scan, R2 structure + all-VALU reduction): 1 WG/batch elem.
// Thread (jg=tid>>3, ks=tid&7): outputs {jg, jg+32, jg+64, jg+96} over
// k in [ks*16, ks*16+16). Reduction over ks entirely on the VALU pipe
// (xor1, xor2 quad_perm + row_half_mirror) — no ds_swizzle latency.
// h double-buffered in LDS; one lgkm-only barrier/step; z prefetch 8 deep;
// only 2 vmem ops/step/writer-thread (pipelines cleanly, unlike R4).
// ---------------------------------------------------------------------------
__global__ __launch_bounds__(256) void k_scan(const float* __restrict__ Whh,
                                              float* __restrict__ Z)
{
  __shared__ __align__(16) float hbuf[2][128];
  const int tid = threadIdx.x;
  const int b   = blockIdx.x;
  const int jg  = tid >> 3;      // 0..31
  const int ks  = tid & 7;       // 0..7
  const int k0  = ks * 16;

  float4 w[4][4];
#pragma unroll
  for (int r = 0; r < 4; ++r) {
    const float4* wg = (const float4*)(Whh + (jg + r*32)*H_DIM + k0);
#pragma unroll
    for (int m = 0; m < 4; ++m) w[r][m] = wg[m];
  }

  if (tid < 128) { hbuf[0][tid] = 0.f; }

  const bool writer = (ks < 4);
  const int  j_out  = jg + ks*32;
  float* zp = Z + b*H_DIM + j_out;

  float zbuf[8];
#pragma unroll
  for (int i = 0; i < 8; ++i) zbuf[i] = writer ? zp[i * 32768] : 0.f;

  barrier_lds_only();

  for (int tb = 0; tb < T_SEQ; tb += 8) {
#pragma unroll
    for (int u = 0; u < 8; ++u) {
      const int t = tb + u;
      const float* h = hbuf[t & 1];
      float4 h0 = *(const float4*)&h[k0];
      float4 h1 = *(const float4*)&h[k0 + 4];
      float4 h2 = *(const float4*)&h[k0 + 8];
      float4 h3 = *(const float4*)&h[k0 + 12];

      float a[4];
#pragma unroll
      for (int r = 0; r < 4; ++r) {
        float p0 = dot4(w[r][0], h0);
        float p1 = dot4(w[r][1], h1);
        float p2 = dot4(w[r][2], h2);
        float p3 = dot4(w[r][3], h3);
        a[r] = (p0 + p1) + (p2 + p3);
      }
#pragma unroll
      for (int r = 0; r < 4; ++r) {
        a[r] = add_xor1(a[r]);
        a[r] = add_xor2(a[r]);
        a[r] = add_mirror8(a[r]);   // VALU-only: lane^7 == lane^4 here
      }
      if (writer) {
        float v  = a[ks] + zbuf[u];
        float hn = fast_tanh(v);
        hbuf[(t & 1) ^ 1][j_out] = hn;
        zp[t * 32768] = hn;
        zbuf[u] = (t + 8 < T_SEQ) ? zp[(t + 8) * 32768] : 0.f;
      }
      barrier_lds_only();
    }
  }
}

// ---------------------------------------------------------------------------
// Kernel 3 (f16 MFMA): y = tanh(h Wh^T + bh) Wg^T + bg.  (unchanged from R4)
// ---------------------------------------------------------------------------
#define TILE_R 64
#define TPW    8
#define HM_S   136
#define WH_S   136

__global__ __launch_bounds__(256) void k_out_mfma(
    const float* __restrict__ Zh, const float* __restrict__ Wh,
    const float* __restrict__ bh, const float* __restrict__ Wg,
    const float* __restrict__ bg, float* __restrict__ y)
{
  __shared__ __align__(16) _Float16 wh_l[128 * WH_S];    // 34816 B
  __shared__ __align__(16) _Float16 hm_l[TILE_R * HM_S]; // 17408 B

  const int tid = threadIdx.x;
  const int l   = tid & 63;
  const int wv  = tid >> 6;
  const int ln  = l & 15;
  const int kg  = l >> 4;

  {
    const float4* wg4 = (const float4*)Wh;
#pragma unroll
    for (int p = 0; p < 16; ++p) {
      int f = tid + p * 256;
      int row = f >> 5, kc = (f & 31) * 4;
      float4 v = wg4[f];
      half4 s = { (_Float16)v.x, (_Float16)v.y, (_Float16)v.z, (_Float16)v.w };
      *(half4*)&wh_l[row * WH_S + kc] = s;
    }
  }

  half8 wg_r[4][4];
#pragma unroll
  for (int nt2 = 0; nt2 < 4; ++nt2)
#pragma unroll
    for (int ks = 0; ks < 4; ++ks) {
      const float* wp = Wg + (nt2*16 + ln) * H_DIM + ks*32 + kg*8;
      wg_r[nt2][ks] = pack_h8(*(const float4*)wp, *(const float4*)(wp + 4));
    }

  float bh_r[8], bg_r[4];
#pragma unroll
  for (int nt = 0; nt < 8; ++nt) bh_r[nt] = bh[nt*16 + ln];
#pragma unroll
  for (int nt2 = 0; nt2 < 4; ++nt2) bg_r[nt2] = bg[nt2*16 + ln];

  for (int it = 0; it < TPW; ++it) {
    const int tile = blockIdx.x * TPW + it;
    const long r0  = (long)tile * TILE_R;
    const bool zero = (tile < 4);        // rows < 256 -> t==0 -> h = 0

    {
      const float4* hg = (const float4*)(Zh + (r0 - 256) * H_DIM);
#pragma unroll
      for (int p = 0; p < 8; ++p) {
        int f = tid + p * 256;
        int row = f >> 5, kc = (f & 31) * 4;
        float4 v;
        if (zero) { v.x = v.y = v.z = v.w = 0.f; } else { v = hg[f]; }
        half4 s = { (_Float16)v.x, (_Float16)v.y, (_Float16)v.z, (_Float16)v.w };
        *(half4*)&hm_l[row * HM_S + kc] = s;
      }
    }
    barrier_lds_only();

    half8 af[4];
#pragma unroll
    for (int ks = 0; ks < 4; ++ks)
      af[ks] = *(const half8*)&hm_l[(wv*16 + ln) * HM_S + ks*32 + kg*8];

#pragma unroll
    for (int nt = 0; nt < 8; ++nt) {
      f32x4 acc = {0.f, 0.f, 0.f, 0.f};
#pragma unroll
      for (int ks = 0; ks < 4; ++ks) {
        half8 bf = *(const half8*)&wh_l[(nt*16 + ln) * WH_S + ks*32 + kg*8];
        acc = __builtin_amdgcn_mfma_f32_16x16x32_f16(af[ks], bf, acc, 0, 0, 0);
      }
#pragma unroll
      for (int c = 0; c < 4; ++c) {
        float val = fast_tanh(acc[c] + bh_r[nt]);
        hm_l[(wv*16 + kg*4 + c) * HM_S + nt*16 + ln] = (_Float16)val;
      }
    }

    half8 a2[4];
#pragma unroll
    for (int ks = 0; ks < 4; ++ks)
      a2[ks] = *(const half8*)&hm_l[(wv*16 + ln) * HM_S + ks*32 + kg*8];

#pragma unroll
    for (int nt2 = 0; nt2 < 4; ++nt2) {
      f32x4 acc2 = { bg_r[nt2], bg_r[nt2], bg_r[nt2], bg_r[nt2] };
#pragma unroll
      for (int ks = 0; ks < 4; ++ks)
        acc2 = __builtin_amdgcn_mfma_f32_16x16x32_f16(a2[ks], wg_r[nt2][ks],
                                                      acc2, 0, 0, 0);
#pragma unroll
      for (int c = 0; c < 4; ++c)
        y[(r0 + wv*16 + kg*4 + c) * D_IN + nt2*16 + ln] = acc2[c];
    }
    barrier_lds_only();
  }
}

extern "C" void kernel_launch(void* const* d_in, const int* in_sizes, int n_in,
                              void* d_out, int out_size, void* d_ws, size_t ws_size,
                              hipStream_t stream) {
  const float* x   = (const float*)d_in[0];
  const float* Wx  = (const float*)d_in[1];
  const float* bx  = (const float*)d_in[2];
  const float* Wih = (const float*)d_in[3];
  const float* bih = (const float*)d_in[4];
  const float* Whh = (const float*)d_in[5];
  const float* bhh = (const float*)d_in[6];
  const float* Wh  = (const float*)d_in[7];
  const float* bh  = (const float*)d_in[8];
  const float* Wg  = (const float*)d_in[9];
  const float* bg  = (const float*)d_in[10];
  float* Z = (float*)d_ws;              // T*B*H*4 = 134,217,728 B
  float* y = (float*)d_out;

  k_feat_mfma<<<512, 256, 0, stream>>>(x, Wx, bx, Wih, bih, bhh, Z);
  k_scan     <<<B_SZ, 256, 0, stream>>>(Whh, Z);
  k_out_mfma <<<512, 256, 0, stream>>>(Z, Wh, bh, Wg, bg, y);
}